// Round 8
// baseline (891.832 us; speedup 1.0000x reference)
//
#include <hip/hip_runtime.h>

typedef __bf16 bf16_t;
typedef bf16_t bf16x8 __attribute__((ext_vector_type(8)));
typedef float f32x4 __attribute__((ext_vector_type(4)));
typedef unsigned short u16;

#define P_TOTAL 98304
#define PTS_PER_BATCH 49152

__device__ __forceinline__ u16 f2bs(float f){ bf16_t b=(bf16_t)f; return __builtin_bit_cast(u16,b); }

// lgkm-only barrier: preserves all LDS hazards but does NOT drain vmcnt ->
// cross-phase weight prefetch stays in flight.
__device__ __forceinline__ void bar_lds(){
  asm volatile("s_waitcnt lgkmcnt(0)" ::: "memory");
  __builtin_amdgcn_s_barrier();
  __builtin_amdgcn_sched_barrier(0);
}

// async global->LDS 16B (no VGPR round-trip). Dest must be wave-uniform base + lane*16.
__device__ __forceinline__ void gload_lds16(const u16* g, u16* l){
  __builtin_amdgcn_global_load_lds((const __attribute__((address_space(1))) void*)g,
                                   (__attribute__((address_space(3))) void*)l, 16, 0, 0);
}

// ---------- weight transform: (K=512,N=512) fp32 -> MFMA-fragment-linear bf16 ----------
// idx = ((nstrip*16 + kt)*2 + nt)*512 + lane*8 + j
//   value = W[k][n],  n = nstrip*32 + nt*16 + (lane&15),  k = kt*32 + (lane>>4)*8 + j
__global__ void k_wtrans15(const float* __restrict__ lz, const float* __restrict__ f0,
                           const float* __restrict__ f1, u16* __restrict__ dst){
  int kt = blockIdx.x, ns = blockIdx.y, z = blockIdx.z;
  const float* src = (z<5) ? (lz + (size_t)z*262144)
                   : (z<10 ? (f0 + (size_t)(z-5)*262144)
                           : (f1 + (size_t)(z-10)*262144));
  u16* d = dst + (size_t)z*262144 + (size_t)(ns*16 + kt)*1024;
  int l = threadIdx.x;
  int col = ns*32 + (l&15);
  int kr  = kt*32 + (l>>4)*8;
  #pragma unroll
  for (int nt=0;nt<2;nt++){
    bf16x8 o;
    #pragma unroll
    for (int j=0;j<8;j++) o[j] = (bf16_t)src[(size_t)(kr+j)*512 + col + nt*16];
    *(bf16x8*)(d + nt*512 + l*8) = o;
  }
}

// lin_in: (63,512) fp32 -> fragment-linear bf16, K padded to 64 (2 kt chunks)
__global__ void k_wtrans_in(const float* __restrict__ w, u16* __restrict__ dst){
  int kt = blockIdx.x, ns = blockIdx.y;
  u16* d = dst + (size_t)(ns*2 + kt)*1024;
  int l = threadIdx.x;
  int col = ns*32 + (l&15);
  int kr  = kt*32 + (l>>4)*8;
  #pragma unroll
  for (int nt=0;nt<2;nt++){
    bf16x8 o;
    #pragma unroll
    for (int j=0;j<8;j++){
      int k = kr + j;
      o[j] = (k < 63) ? (bf16_t)w[(size_t)k*512 + col + nt*16] : (bf16_t)0.f;
    }
    *(bf16x8*)(d + nt*512 + l*8) = o;
  }
}

// ---------- feature transpose: (B,512,128,128) f32 -> (B,128,128,512) bf16 ----------
__global__ void k_featT(const float* __restrict__ feat, u16* __restrict__ featT){
  int x = threadIdx.x;
  int c8 = blockIdx.x*8;
  int y = blockIdx.y, b = blockIdx.z;
  float v[8];
  #pragma unroll
  for (int j=0;j<8;j++)
    v[j] = feat[(((size_t)(b*512 + c8 + j))*128 + y)*128 + x];
  bf16x8 o;
  #pragma unroll
  for (int j=0;j<8;j++) o[j] = (bf16_t)v[j];
  *(bf16x8*)(featT + (((size_t)(b*128 + y))*128 + x)*512 + c8) = o;
}

// ---------- per-point: geometry + bilinear + positional encoding ----------
// 16 points per block (16 waves). Outputs written FRAGMENT-LINEAR (k_net staging
// is a straight linear copy):
//   alignedF idx = (p>>6)*32768 + (kt*4 + ((p>>4)&3))*512 + (fk8*16 + (p&15))*8 + j
//     value = act[p][k = kt*32 + fk8*8 + j]
//   encF    idx = (p>>6)*4096  + (kt*4 + ((p>>4)&3))*512 + (fk8*16 + (p&15))*8 + j  (kt<2)
__global__ __launch_bounds__(1024) void k_points(
    const float* __restrict__ world, const float* __restrict__ c2w,
    const float* __restrict__ kmat, const u16* __restrict__ featT,
    u16* __restrict__ alignedF, u16* __restrict__ encF){
  __shared__ u16 act[16*520];
  __shared__ u16 encs[16*72];
  int wid = threadIdx.x >> 6, lane = threadIdx.x & 63;
  int p0 = blockIdx.x*16;
  int gp = p0 + wid;
  int b = gp / PTS_PER_BATCH;
  const float* wp = world + (size_t)gp*3;
  float px = wp[0], py = wp[1], pz = wp[2];
  const float* cw = c2w + b*16;
  float dx = px - cw[3], dy = py - cw[7], dz = pz - cw[11];
  float cx = cw[0]*dx + cw[4]*dy + cw[8]*dz;
  float cy = cw[1]*dx + cw[5]*dy + cw[9]*dz;
  float cz = cw[2]*dx + cw[6]*dy + cw[10]*dz;
  const float* km = kmat + b*9;
  float u0 = km[0]*cx + km[1]*cy + km[2]*cz;
  float v0 = km[3]*cx + km[4]*cy + km[5]*cz;
  float zz = km[6]*cx + km[7]*cy + km[8]*cz;
  if (fabsf(zz) < 1e-6f) zz = 1e-6f;
  float uu = u0/zz, vv = v0/zz;
  float xf = fminf(fmaxf(uu, 0.f), 127.f);
  float yf = fminf(fmaxf(vv, 0.f), 127.f);
  float x0f = floorf(xf), y0f = floorf(yf);
  int x0 = (int)x0f, y0 = (int)y0f;
  int x1 = min(x0+1,127), y1 = min(y0+1,127);
  float wx = xf - x0f, wy = yf - y0f;
  float w00 = (1.f-wx)*(1.f-wy), w01 = wx*(1.f-wy), w10 = (1.f-wx)*wy, w11 = wx*wy;
  size_t fb = (size_t)b*128*128*512;
  int c8 = lane*8;
  const bf16x8 t00 = *(const bf16x8*)(featT + fb + (size_t)(y0*128+x0)*512 + c8);
  const bf16x8 t01 = *(const bf16x8*)(featT + fb + (size_t)(y0*128+x1)*512 + c8);
  const bf16x8 t10 = *(const bf16x8*)(featT + fb + (size_t)(y1*128+x0)*512 + c8);
  const bf16x8 t11 = *(const bf16x8*)(featT + fb + (size_t)(y1*128+x1)*512 + c8);
  bf16x8 o;
  #pragma unroll
  for (int j=0;j<8;j++){
    float r = (float)t00[j]*w00 + (float)t01[j]*w01 + (float)t10[j]*w10 + (float)t11[j]*w11;
    o[j] = (bf16_t)r;
  }
  *(bf16x8*)&act[wid*520 + lane*8] = o;
  float cam[3] = {cx, cy, cz};
  float e;
  if (lane < 3) e = cam[lane];
  else if (lane < 33){
    int i = (lane-3)/10, f = (lane-3)%10;
    e = sinf(6.2831855f * cam[i] * (float)(1<<f));
  } else if (lane < 63){
    int i = (lane-33)/10, f = (lane-33)%10;
    e = cosf(6.2831855f * cam[i] * (float)(1<<f));
  } else e = 0.f;
  encs[wid*72 + lane] = f2bs(e);
  __syncthreads();
  int t = threadIdx.x;
  int g = blockIdx.x & 3;
  size_t blk = (size_t)(blockIdx.x >> 2);
  {
    int kt = t>>6, lo = t&63, fm = lo&15, fk8 = lo>>4;
    bf16x8 v = *(const bf16x8*)&act[fm*520 + kt*32 + fk8*8];
    *(bf16x8*)(alignedF + blk*32768 + (size_t)(kt*4+g)*512 + lo*8) = v;
  }
  if (t < 128){
    int kt = t>>6, lo = t&63, fm = lo&15, fk8 = lo>>4;
    bf16x8 v = *(const bf16x8*)&encs[fm*72 + kt*32 + fk8*8];
    *(bf16x8*)(encF + blk*4096 + (size_t)(kt*4+g)*512 + lo*8) = v;
  }
}

// ============ fused persistent MLP: 1024 thr (16 waves, 4/SIMD), M=64/block ============
// Round-8 cleanup of the 16-wave geometry:
//  - staging via global_load_lds (no VGPR round-trip -> kills round-7's 61MB spill)
//  - rotation dropped: all kt offsets are compile-time immediates off 2 running ptrs
//  - br double-buffer with loads issued BEFORE the MFMA cluster (135cy cover > 120cy ds)
//  - keeps: fragment-linear weights + LDS, lgkm-only barriers, 2-deep A-prefetch
//    crossing phase boundaries, setprio around MFMA clusters.
// C[n][m]: lane holds m = bt*16+(l&15); reg r holds n = w*32 + nt*16 + (l>>4)*4 + r.

#define MFMA_BF16(A,B,C) __builtin_amdgcn_mfma_f32_16x16x32_bf16(A,B,C,0,0,0)

__device__ __forceinline__ void mfma_cluster(const bf16x8& a0, const bf16x8& a1,
                                             const bf16x8* br, f32x4 (&acc)[4][2]){
  __builtin_amdgcn_s_setprio(1);
  #pragma unroll
  for (int q=0;q<4;q++){
    acc[q][0] = MFMA_BF16(a0, br[q], acc[q][0]);
    acc[q][1] = MFMA_BF16(a1, br[q], acc[q][1]);
  }
  __builtin_amdgcn_s_setprio(0);
}

template<int NK>
__device__ __forceinline__ void gemm5(const u16* bp, const u16* __restrict__ apS,
                                      const u16* __restrict__ apN,
                                      f32x4 (&acc)[4][2], bf16x8 (&a)[2][2]){
  // bp = LDS buf + l*8 (thread base); apS/apN = weight stream base + l*8.
  // entry: a[d] holds this gemm's A-fragments for kt=d.
  bf16x8 br[2][4];
  #pragma unroll
  for (int q=0;q<4;q++) br[0][q] = *(const bf16x8*)(bp + q*512);
  #pragma unroll 1
  for (int kb=0; kb<NK/2-1; ++kb){
    const u16* bk = bp  + kb*4096;
    const u16* ak = apS + kb*2048;
    // kt = 2kb: prefetch br(kt+1) first, then MFMA, then A(kt+2)
    #pragma unroll
    for (int q=0;q<4;q++) br[1][q] = *(const bf16x8*)(bk + 2048 + q*512);
    mfma_cluster(a[0][0], a[0][1], br[0], acc);
    a[0][0] = *(const bf16x8*)(ak + 2048);
    a[0][1] = *(const bf16x8*)(ak + 2048 + 512);
    // kt = 2kb+1
    #pragma unroll
    for (int q=0;q<4;q++) br[0][q] = *(const bf16x8*)(bk + 4096 + q*512);
    mfma_cluster(a[1][0], a[1][1], br[1], acc);
    a[1][0] = *(const bf16x8*)(ak + 3072);
    a[1][1] = *(const bf16x8*)(ak + 3072 + 512);
  }
  { // tail: kt = NK-2, NK-1; A-prefetch targets the NEXT phase (kt'=0,1)
    const u16* bk = bp + (NK/2-1)*4096;
    #pragma unroll
    for (int q=0;q<4;q++) br[1][q] = *(const bf16x8*)(bk + 2048 + q*512);
    mfma_cluster(a[0][0], a[0][1], br[0], acc);
    a[0][0] = *(const bf16x8*)(apN);
    a[0][1] = *(const bf16x8*)(apN + 512);
    mfma_cluster(a[1][0], a[1][1], br[1], acc);
    a[1][0] = *(const bf16x8*)(apN + 1024);
    a[1][1] = *(const bf16x8*)(apN + 1536);
  }
}

__device__ __forceinline__ void add_bias4(const float* __restrict__ bias, int wn32, int rq,
                                          f32x4 (&acc)[4][2]){
  #pragma unroll
  for (int nt=0; nt<2; ++nt){
    f32x4 bv = *(const f32x4*)&bias[wn32 + nt*16 + rq];
    #pragma unroll
    for (int bt=0; bt<4; ++bt)
      #pragma unroll
      for (int r=0; r<4; ++r)
        acc[bt][nt][r] += bv[r];
  }
}

// write relu(acc) into fragment-linear bufB. Wave w owns k-chunk w (n=32 strip):
// k = w*32 + nt*16 + fk8*4 + r  ->  chunk=w, lane' = (nt*2+(fk8>>1))*16 + fm,
// j = (fk8&1)*4 + r.  All offsets immediate off one thread base; conflict-free b64.
__device__ __forceinline__ void write_relu4(u16* dst, int w, int fm, int fk8,
                                            f32x4 (&acc)[4][2]){
  u16* base = dst + w*2048 + (fk8>>1)*128 + fm*8 + (fk8&1)*4;
  #pragma unroll
  for (int bt=0; bt<4; ++bt)
    #pragma unroll
    for (int nt=0; nt<2; ++nt){
      u16 p0 = f2bs(fmaxf(acc[bt][nt][0], 0.f));
      u16 p1 = f2bs(fmaxf(acc[bt][nt][1], 0.f));
      u16 p2 = f2bs(fmaxf(acc[bt][nt][2], 0.f));
      u16 p3 = f2bs(fmaxf(acc[bt][nt][3], 0.f));
      uint2 v;
      v.x = (unsigned)p0 | ((unsigned)p1 << 16);
      v.y = (unsigned)p2 | ((unsigned)p3 << 16);
      *(uint2*)(base + bt*512 + nt*256) = v;
    }
}

__global__ __launch_bounds__(1024, 4) void k_net(
    const u16* __restrict__ alignedF, const u16* __restrict__ encF,
    const u16* __restrict__ wtin, const float* __restrict__ b_in,
    const u16* __restrict__ wts, const float* __restrict__ bz,
    const float* __restrict__ b0, const float* __restrict__ b1,
    const float* __restrict__ wout, const float* __restrict__ bout,
    float* __restrict__ out)
{
  __shared__ u16 bufA[32768];   // aligned, fragment-linear (64 KB, persistent)
  __shared__ u16 bufB[32768];   // activations, fragment-linear (64 KB)
  const int t = threadIdx.x, w = t>>6, l = t&63;
  const int fm = l&15, fk8 = l>>4, rq = fk8*4;
  const int wn32 = w*32;

  // async staging: global -> LDS direct (linear layouts; no VGPR round-trip)
  {
    const u16* srcA = alignedF + (size_t)blockIdx.x*32768;
    #pragma unroll
    for (int j=0;j<4;j++)
      gload_lds16(srcA + j*8192 + t*8, bufA + j*8192 + t*8);
    if (t < 512){
      const u16* srcE = encF + (size_t)blockIdx.x*4096;
      gload_lds16(srcE + t*8, bufB + t*8);
    }
  }
  asm volatile("s_waitcnt vmcnt(0)" ::: "memory");
  __builtin_amdgcn_s_barrier();
  __builtin_amdgcn_sched_barrier(0);

  // preload A-fragments for the enc-gemm
  const u16* apEl = wtin + (size_t)w*2048 + l*8;
  bf16x8 a[2][2];
  a[0][0] = *(const bf16x8*)(apEl);        a[0][1] = *(const bf16x8*)(apEl + 512);
  a[1][0] = *(const bf16x8*)(apEl + 1024); a[1][1] = *(const bf16x8*)(apEl + 1536);

  f32x4 h[4][2] = {};
  gemm5<2>(bufB + l*8, apEl, wts + (size_t)w*16384 + l*8, h, a);
  add_bias4(b_in, wn32, rq, h);

  #pragma unroll 1
  for (int i=0;i<5;i++){
    const u16* apz  = wts + (size_t)i*262144      + (size_t)w*16384 + l*8;
    const u16* apf0 = wts + (size_t)(5+i)*262144  + (size_t)w*16384 + l*8;
    const u16* apf1 = wts + (size_t)(10+i)*262144 + (size_t)w*16384 + l*8;
    const u16* apzn = (i<4) ? (wts + (size_t)(i+1)*262144 + (size_t)w*16384 + l*8) : apEl;

    gemm5<16>(bufA + l*8, apz, apf0, h, a);          // h += aligned @ Wz
    add_bias4(bz + i*512, wn32, rq, h);
    bar_lds();                                       // prior bufB readers done
    write_relu4(bufB, w, fm, fk8, h);                // bufB = relu(h)
    bar_lds();
    f32x4 acc[4][2] = {};
    gemm5<16>(bufB + l*8, apf0, apf1, acc, a);       // net = relu(h) @ W0
    add_bias4(b0 + i*512, wn32, rq, acc);
    bar_lds();                                       // all fc0 reads of bufB done
    write_relu4(bufB, w, fm, fk8, acc);              // bufB = relu(net)
    bar_lds();
    gemm5<16>(bufB + l*8, apf1, apzn, h, a);         // h += relu(net) @ W1
    add_bias4(b1 + i*512, wn32, rq, h);
  }

  // sigma = exp(relu(h) . wout + bout); per lane: 4 m-cols (bt), 8 n-rows (nt,r)
  float s[4];
  {
    #pragma unroll
    for (int bt=0; bt<4; ++bt) s[bt] = 0.f;
    #pragma unroll
    for (int nt=0; nt<2; ++nt){
      f32x4 wv = *(const f32x4*)&wout[wn32 + nt*16 + rq];
      #pragma unroll
      for (int bt=0; bt<4; ++bt)
        #pragma unroll
        for (int r=0; r<4; ++r)
          s[bt] += fmaxf(h[bt][nt][r], 0.f) * wv[r];
    }
  }
  #pragma unroll
  for (int bt=0; bt<4; ++bt){
    s[bt] += __shfl_xor(s[bt], 16, 64);    // fold the 4 fk8 groups
    s[bt] += __shfl_xor(s[bt], 32, 64);
  }
  bar_lds();                       // all fc1 reads of bufB done; reuse as red[16][64]
  float* red = (float*)bufB;
  if (l < 16){
    #pragma unroll
    for (int bt=0; bt<4; ++bt)
      red[w*64 + bt*16 + l] = s[bt];
  }
  bar_lds();
  if (t < 64){
    float aa = bout[0];
    #pragma unroll
    for (int wv=0; wv<16; wv++) aa += red[wv*64 + t];
    out[blockIdx.x*64 + t] = expf(aa);
  }
}

extern "C" void kernel_launch(void* const* d_in, const int* in_sizes, int n_in,
                              void* d_out, int out_size, void* d_ws, size_t ws_size,
                              hipStream_t stream) {
  const float* world = (const float*)d_in[0];
  const float* c2w   = (const float*)d_in[1];
  const float* kmat  = (const float*)d_in[2];
  const float* feat  = (const float*)d_in[3];
  const float* w_in  = (const float*)d_in[4];
  const float* b_in  = (const float*)d_in[5];
  const float* w_z   = (const float*)d_in[6];
  const float* b_z   = (const float*)d_in[7];
  const float* w_f0  = (const float*)d_in[8];
  const float* b_f0  = (const float*)d_in[9];
  const float* w_f1  = (const float*)d_in[10];
  const float* b_f1  = (const float*)d_in[11];
  const float* w_out = (const float*)d_in[12];
  const float* b_out = (const float*)d_in[13];
  float* out = (float*)d_out;
  char* ws = (char*)d_ws;

  size_t off = 0;
  u16* wts   = (u16*)(ws + off); off += (size_t)15*262144*2;       // 15x fragment-linear bf16
  u16* wtin  = (u16*)(ws + off); off += (size_t)512*64*2;          // lin_in fragment-linear bf16
  u16* featT = (u16*)(ws + off); off += (size_t)2*128*128*512*2;   // transposed features
  u16* alignedF = (u16*)(ws + off); off += (size_t)P_TOTAL*512*2;  // sampled feats, frag-linear
  u16* encF  = (u16*)(ws + off); off += (size_t)P_TOTAL*64*2;      // pos-enc, frag-linear

  k_wtrans15<<<dim3(16,16,15), 64, 0, stream>>>(w_z, w_f0, w_f1, wts);
  k_wtrans_in<<<dim3(2,16,1), 64, 0, stream>>>(w_in, wtin);
  k_featT<<<dim3(64,128,2), 128, 0, stream>>>(feat, featT);
  k_points<<<dim3(P_TOTAL/16), 1024, 0, stream>>>(world, c2w, kmat, featT, alignedF, encF);
  k_net<<<dim3(P_TOTAL/64), 1024, 0, stream>>>(alignedF, encF, wtin, b_in, wts,
      b_z, b_f0, b_f1, w_out, b_out, out);
}

// Round 9
// 834.258 us; speedup vs baseline: 1.0690x; 1.0690x over previous
//
#include <hip/hip_runtime.h>

typedef __bf16 bf16_t;
typedef bf16_t bf16x8 __attribute__((ext_vector_type(8)));
typedef float f32x4 __attribute__((ext_vector_type(4)));
typedef unsigned short u16;

#define P_TOTAL 98304
#define PTS_PER_BATCH 49152

__device__ __forceinline__ u16 f2bs(float f){ bf16_t b=(bf16_t)f; return __builtin_bit_cast(u16,b); }

// lgkm-only barrier: preserves all LDS hazards but does NOT drain vmcnt ->
// cross-phase weight prefetch stays in flight.
__device__ __forceinline__ void bar_lds(){
  asm volatile("s_waitcnt lgkmcnt(0)" ::: "memory");
  __builtin_amdgcn_s_barrier();
  __builtin_amdgcn_sched_barrier(0);
}

// async global->LDS 16B (no VGPR round-trip). Dest must be wave-uniform base + lane*16.
__device__ __forceinline__ void gload_lds16(const u16* g, u16* l){
  __builtin_amdgcn_global_load_lds((const __attribute__((address_space(1))) void*)g,
                                   (__attribute__((address_space(3))) void*)l, 16, 0, 0);
}

// ---------- weight transform: (K=512,N=512) fp32 -> MFMA-fragment-linear bf16 ----------
// idx = ((nstrip*16 + kt)*2 + nt)*512 + lane*8 + j
//   value = W[k][n],  n = nstrip*32 + nt*16 + (lane&15),  k = kt*32 + (lane>>4)*8 + j
__global__ void k_wtrans15(const float* __restrict__ lz, const float* __restrict__ f0,
                           const float* __restrict__ f1, u16* __restrict__ dst){
  int kt = blockIdx.x, ns = blockIdx.y, z = blockIdx.z;
  const float* src = (z<5) ? (lz + (size_t)z*262144)
                   : (z<10 ? (f0 + (size_t)(z-5)*262144)
                           : (f1 + (size_t)(z-10)*262144));
  u16* d = dst + (size_t)z*262144 + (size_t)(ns*16 + kt)*1024;
  int l = threadIdx.x;
  int col = ns*32 + (l&15);
  int kr  = kt*32 + (l>>4)*8;
  #pragma unroll
  for (int nt=0;nt<2;nt++){
    bf16x8 o;
    #pragma unroll
    for (int j=0;j<8;j++) o[j] = (bf16_t)src[(size_t)(kr+j)*512 + col + nt*16];
    *(bf16x8*)(d + nt*512 + l*8) = o;
  }
}

// lin_in: (63,512) fp32 -> fragment-linear bf16, K padded to 64 (2 kt chunks)
__global__ void k_wtrans_in(const float* __restrict__ w, u16* __restrict__ dst){
  int kt = blockIdx.x, ns = blockIdx.y;
  u16* d = dst + (size_t)(ns*2 + kt)*1024;
  int l = threadIdx.x;
  int col = ns*32 + (l&15);
  int kr  = kt*32 + (l>>4)*8;
  #pragma unroll
  for (int nt=0;nt<2;nt++){
    bf16x8 o;
    #pragma unroll
    for (int j=0;j<8;j++){
      int k = kr + j;
      o[j] = (k < 63) ? (bf16_t)w[(size_t)k*512 + col + nt*16] : (bf16_t)0.f;
    }
    *(bf16x8*)(d + nt*512 + l*8) = o;
  }
}

// ---------- feature transpose: (B,512,128,128) f32 -> (B,128,128,512) bf16 ----------
__global__ void k_featT(const float* __restrict__ feat, u16* __restrict__ featT){
  int x = threadIdx.x;
  int c8 = blockIdx.x*8;
  int y = blockIdx.y, b = blockIdx.z;
  float v[8];
  #pragma unroll
  for (int j=0;j<8;j++)
    v[j] = feat[(((size_t)(b*512 + c8 + j))*128 + y)*128 + x];
  bf16x8 o;
  #pragma unroll
  for (int j=0;j<8;j++) o[j] = (bf16_t)v[j];
  *(bf16x8*)(featT + (((size_t)(b*128 + y))*128 + x)*512 + c8) = o;
}

// ---------- per-point: geometry + bilinear + positional encoding ----------
// 16 points per block (16 waves). Outputs written FRAGMENT-LINEAR (k_net staging
// is a straight linear copy):
//   alignedF idx = (p>>6)*32768 + (kt*4 + ((p>>4)&3))*512 + (fk8*16 + (p&15))*8 + j
//     value = act[p][k = kt*32 + fk8*8 + j]
//   encF    idx = (p>>6)*4096  + (kt*4 + ((p>>4)&3))*512 + (fk8*16 + (p&15))*8 + j  (kt<2)
__global__ __launch_bounds__(1024) void k_points(
    const float* __restrict__ world, const float* __restrict__ c2w,
    const float* __restrict__ kmat, const u16* __restrict__ featT,
    u16* __restrict__ alignedF, u16* __restrict__ encF){
  __shared__ u16 act[16*520];
  __shared__ u16 encs[16*72];
  int wid = threadIdx.x >> 6, lane = threadIdx.x & 63;
  int p0 = blockIdx.x*16;
  int gp = p0 + wid;
  int b = gp / PTS_PER_BATCH;
  const float* wp = world + (size_t)gp*3;
  float px = wp[0], py = wp[1], pz = wp[2];
  const float* cw = c2w + b*16;
  float dx = px - cw[3], dy = py - cw[7], dz = pz - cw[11];
  float cx = cw[0]*dx + cw[4]*dy + cw[8]*dz;
  float cy = cw[1]*dx + cw[5]*dy + cw[9]*dz;
  float cz = cw[2]*dx + cw[6]*dy + cw[10]*dz;
  const float* km = kmat + b*9;
  float u0 = km[0]*cx + km[1]*cy + km[2]*cz;
  float v0 = km[3]*cx + km[4]*cy + km[5]*cz;
  float zz = km[6]*cx + km[7]*cy + km[8]*cz;
  if (fabsf(zz) < 1e-6f) zz = 1e-6f;
  float uu = u0/zz, vv = v0/zz;
  float xf = fminf(fmaxf(uu, 0.f), 127.f);
  float yf = fminf(fmaxf(vv, 0.f), 127.f);
  float x0f = floorf(xf), y0f = floorf(yf);
  int x0 = (int)x0f, y0 = (int)y0f;
  int x1 = min(x0+1,127), y1 = min(y0+1,127);
  float wx = xf - x0f, wy = yf - y0f;
  float w00 = (1.f-wx)*(1.f-wy), w01 = wx*(1.f-wy), w10 = (1.f-wx)*wy, w11 = wx*wy;
  size_t fb = (size_t)b*128*128*512;
  int c8 = lane*8;
  const bf16x8 t00 = *(const bf16x8*)(featT + fb + (size_t)(y0*128+x0)*512 + c8);
  const bf16x8 t01 = *(const bf16x8*)(featT + fb + (size_t)(y0*128+x1)*512 + c8);
  const bf16x8 t10 = *(const bf16x8*)(featT + fb + (size_t)(y1*128+x0)*512 + c8);
  const bf16x8 t11 = *(const bf16x8*)(featT + fb + (size_t)(y1*128+x1)*512 + c8);
  bf16x8 o;
  #pragma unroll
  for (int j=0;j<8;j++){
    float r = (float)t00[j]*w00 + (float)t01[j]*w01 + (float)t10[j]*w10 + (float)t11[j]*w11;
    o[j] = (bf16_t)r;
  }
  *(bf16x8*)&act[wid*520 + lane*8] = o;
  float cam[3] = {cx, cy, cz};
  float e;
  if (lane < 3) e = cam[lane];
  else if (lane < 33){
    int i = (lane-3)/10, f = (lane-3)%10;
    e = sinf(6.2831855f * cam[i] * (float)(1<<f));
  } else if (lane < 63){
    int i = (lane-33)/10, f = (lane-33)%10;
    e = cosf(6.2831855f * cam[i] * (float)(1<<f));
  } else e = 0.f;
  encs[wid*72 + lane] = f2bs(e);
  __syncthreads();
  int t = threadIdx.x;
  int g = blockIdx.x & 3;
  size_t blk = (size_t)(blockIdx.x >> 2);
  {
    int kt = t>>6, lo = t&63, fm = lo&15, fk8 = lo>>4;
    bf16x8 v = *(const bf16x8*)&act[fm*520 + kt*32 + fk8*8];
    *(bf16x8*)(alignedF + blk*32768 + (size_t)(kt*4+g)*512 + lo*8) = v;
  }
  if (t < 128){
    int kt = t>>6, lo = t&63, fm = lo&15, fk8 = lo>>4;
    bf16x8 v = *(const bf16x8*)&encs[fm*72 + kt*32 + fk8*8];
    *(bf16x8*)(encF + blk*4096 + (size_t)(kt*4+g)*512 + lo*8) = v;
  }
}

// ============ fused persistent MLP: 1024 thr (16 waves, 4/SIMD), M=64/block ============
// Round-9: register-lean K-loop (round-2 profile) inside the round-8 structure.
//  - br[4] SCOPED per kt-step (16 transient VGPRs; compiler schedules ds_reads ahead
//    itself — manual double-buffer caused the round-7/8 loop spill at the 128-reg cap)
//  - a[2][2] depth-2 weight prefetch only (16 VGPRs), crossing phase boundaries
//  - staging via global_load_lds; all kt offsets compile-time immediates
//  - fragment-linear weights + LDS (conflict-free), lgkm-only barriers, setprio.
// Arch-VGPR steady state ~56 < 64; acc-class 64 (h+acc) -> fits 128 regs, no spill.
// C[n][m]: lane holds m = bt*16+(l&15); reg r holds n = w*32 + nt*16 + (l>>4)*4 + r.

#define MFMA_BF16(A,B,C) __builtin_amdgcn_mfma_f32_16x16x32_bf16(A,B,C,0,0,0)

__device__ __forceinline__ void mfma_cluster(const bf16x8& a0, const bf16x8& a1,
                                             const bf16x8 (&br)[4], f32x4 (&acc)[4][2]){
  __builtin_amdgcn_s_setprio(1);
  #pragma unroll
  for (int q=0;q<4;q++){
    acc[q][0] = MFMA_BF16(a0, br[q], acc[q][0]);
    acc[q][1] = MFMA_BF16(a1, br[q], acc[q][1]);
  }
  __builtin_amdgcn_s_setprio(0);
}

template<int NK>
__device__ __forceinline__ void gemm6(const u16* bp, const u16* __restrict__ apS,
                                      const u16* __restrict__ apN,
                                      f32x4 (&acc)[4][2], bf16x8 (&a)[2][2]){
  // bp = LDS buf + l*8 (thread base); apS/apN = weight stream base + l*8.
  // entry: a[d] holds this gemm's A-fragments for kt=d.
  #pragma unroll 1
  for (int kb=0; kb<NK/2-1; ++kb){
    const u16* bk = bp  + kb*4096;
    const u16* ak = apS + kb*2048;
    { // kt = 2kb
      bf16x8 br[4];
      #pragma unroll
      for (int q=0;q<4;q++) br[q] = *(const bf16x8*)(bk + q*512);
      mfma_cluster(a[0][0], a[0][1], br, acc);
      a[0][0] = *(const bf16x8*)(ak + 2048);
      a[0][1] = *(const bf16x8*)(ak + 2048 + 512);
    }
    { // kt = 2kb+1
      bf16x8 br[4];
      #pragma unroll
      for (int q=0;q<4;q++) br[q] = *(const bf16x8*)(bk + 2048 + q*512);
      mfma_cluster(a[1][0], a[1][1], br, acc);
      a[1][0] = *(const bf16x8*)(ak + 3072);
      a[1][1] = *(const bf16x8*)(ak + 3072 + 512);
    }
  }
  { // tail: kt = NK-2, NK-1; A-prefetch targets the NEXT phase (kt'=0,1)
    const u16* bk = bp + (NK/2-1)*4096;
    {
      bf16x8 br[4];
      #pragma unroll
      for (int q=0;q<4;q++) br[q] = *(const bf16x8*)(bk + q*512);
      mfma_cluster(a[0][0], a[0][1], br, acc);
      a[0][0] = *(const bf16x8*)(apN);
      a[0][1] = *(const bf16x8*)(apN + 512);
    }
    {
      bf16x8 br[4];
      #pragma unroll
      for (int q=0;q<4;q++) br[q] = *(const bf16x8*)(bk + 2048 + q*512);
      mfma_cluster(a[1][0], a[1][1], br, acc);
      a[1][0] = *(const bf16x8*)(apN + 1024);
      a[1][1] = *(const bf16x8*)(apN + 1536);
    }
  }
}

__device__ __forceinline__ void add_bias4(const float* __restrict__ bias, int wn32, int rq,
                                          f32x4 (&acc)[4][2]){
  #pragma unroll
  for (int nt=0; nt<2; ++nt){
    f32x4 bv = *(const f32x4*)&bias[wn32 + nt*16 + rq];
    #pragma unroll
    for (int bt=0; bt<4; ++bt)
      #pragma unroll
      for (int r=0; r<4; ++r)
        acc[bt][nt][r] += bv[r];
  }
}

// write relu(acc) into fragment-linear bufB. Wave w owns k-chunk w (n=32 strip):
// k = w*32 + nt*16 + fk8*4 + r  ->  chunk=w, lane' = (nt*2+(fk8>>1))*16 + fm,
// j = (fk8&1)*4 + r.  All offsets immediate off one thread base; conflict-free b64.
__device__ __forceinline__ void write_relu4(u16* dst, int w, int fm, int fk8,
                                            f32x4 (&acc)[4][2]){
  u16* base = dst + w*2048 + (fk8>>1)*128 + fm*8 + (fk8&1)*4;
  #pragma unroll
  for (int bt=0; bt<4; ++bt)
    #pragma unroll
    for (int nt=0; nt<2; ++nt){
      u16 p0 = f2bs(fmaxf(acc[bt][nt][0], 0.f));
      u16 p1 = f2bs(fmaxf(acc[bt][nt][1], 0.f));
      u16 p2 = f2bs(fmaxf(acc[bt][nt][2], 0.f));
      u16 p3 = f2bs(fmaxf(acc[bt][nt][3], 0.f));
      uint2 v;
      v.x = (unsigned)p0 | ((unsigned)p1 << 16);
      v.y = (unsigned)p2 | ((unsigned)p3 << 16);
      *(uint2*)(base + bt*512 + nt*256) = v;
    }
}

__global__ __launch_bounds__(1024, 4) void k_net(
    const u16* __restrict__ alignedF, const u16* __restrict__ encF,
    const u16* __restrict__ wtin, const float* __restrict__ b_in,
    const u16* __restrict__ wts, const float* __restrict__ bz,
    const float* __restrict__ b0, const float* __restrict__ b1,
    const float* __restrict__ wout, const float* __restrict__ bout,
    float* __restrict__ out)
{
  __shared__ u16 bufA[32768];   // aligned, fragment-linear (64 KB, persistent)
  __shared__ u16 bufB[32768];   // activations, fragment-linear (64 KB)
  const int t = threadIdx.x, w = t>>6, l = t&63;
  const int fm = l&15, fk8 = l>>4, rq = fk8*4;
  const int wn32 = w*32;

  // async staging: global -> LDS direct (linear layouts; no VGPR round-trip)
  {
    const u16* srcA = alignedF + (size_t)blockIdx.x*32768;
    #pragma unroll
    for (int j=0;j<4;j++)
      gload_lds16(srcA + j*8192 + t*8, bufA + j*8192 + t*8);
    if (t < 512){
      const u16* srcE = encF + (size_t)blockIdx.x*4096;
      gload_lds16(srcE + t*8, bufB + t*8);
    }
  }
  asm volatile("s_waitcnt vmcnt(0)" ::: "memory");
  __builtin_amdgcn_s_barrier();
  __builtin_amdgcn_sched_barrier(0);

  // preload A-fragments for the enc-gemm
  const u16* apEl = wtin + (size_t)w*2048 + l*8;
  bf16x8 a[2][2];
  a[0][0] = *(const bf16x8*)(apEl);        a[0][1] = *(const bf16x8*)(apEl + 512);
  a[1][0] = *(const bf16x8*)(apEl + 1024); a[1][1] = *(const bf16x8*)(apEl + 1536);

  f32x4 h[4][2] = {};
  gemm6<2>(bufB + l*8, apEl, wts + (size_t)w*16384 + l*8, h, a);
  add_bias4(b_in, wn32, rq, h);

  #pragma unroll 1
  for (int i=0;i<5;i++){
    const u16* apz  = wts + (size_t)i*262144      + (size_t)w*16384 + l*8;
    const u16* apf0 = wts + (size_t)(5+i)*262144  + (size_t)w*16384 + l*8;
    const u16* apf1 = wts + (size_t)(10+i)*262144 + (size_t)w*16384 + l*8;
    const u16* apzn = (i<4) ? (wts + (size_t)(i+1)*262144 + (size_t)w*16384 + l*8) : apEl;

    gemm6<16>(bufA + l*8, apz, apf0, h, a);          // h += aligned @ Wz
    add_bias4(bz + i*512, wn32, rq, h);
    bar_lds();                                       // prior bufB readers done
    write_relu4(bufB, w, fm, fk8, h);                // bufB = relu(h)
    bar_lds();
    f32x4 acc[4][2] = {};
    gemm6<16>(bufB + l*8, apf0, apf1, acc, a);       // net = relu(h) @ W0
    add_bias4(b0 + i*512, wn32, rq, acc);
    bar_lds();                                       // all fc0 reads of bufB done
    write_relu4(bufB, w, fm, fk8, acc);              // bufB = relu(net)
    bar_lds();
    gemm6<16>(bufB + l*8, apf1, apzn, h, a);         // h += relu(net) @ W1
    add_bias4(b1 + i*512, wn32, rq, h);
  }

  // sigma = exp(relu(h) . wout + bout); per lane: 4 m-cols (bt), 8 n-rows (nt,r)
  float s[4];
  {
    #pragma unroll
    for (int bt=0; bt<4; ++bt) s[bt] = 0.f;
    #pragma unroll
    for (int nt=0; nt<2; ++nt){
      f32x4 wv = *(const f32x4*)&wout[wn32 + nt*16 + rq];
      #pragma unroll
      for (int bt=0; bt<4; ++bt)
        #pragma unroll
        for (int r=0; r<4; ++r)
          s[bt] += fmaxf(h[bt][nt][r], 0.f) * wv[r];
    }
  }
  #pragma unroll
  for (int bt=0; bt<4; ++bt){
    s[bt] += __shfl_xor(s[bt], 16, 64);    // fold the 4 fk8 groups
    s[bt] += __shfl_xor(s[bt], 32, 64);
  }
  bar_lds();                       // all fc1 reads of bufB done; reuse as red[16][64]
  float* red = (float*)bufB;
  if (l < 16){
    #pragma unroll
    for (int bt=0; bt<4; ++bt)
      red[w*64 + bt*16 + l] = s[bt];
  }
  bar_lds();
  if (t < 64){
    float aa = bout[0];
    #pragma unroll
    for (int wv=0; wv<16; wv++) aa += red[wv*64 + t];
    out[blockIdx.x*64 + t] = expf(aa);
  }
}

extern "C" void kernel_launch(void* const* d_in, const int* in_sizes, int n_in,
                              void* d_out, int out_size, void* d_ws, size_t ws_size,
                              hipStream_t stream) {
  const float* world = (const float*)d_in[0];
  const float* c2w   = (const float*)d_in[1];
  const float* kmat  = (const float*)d_in[2];
  const float* feat  = (const float*)d_in[3];
  const float* w_in  = (const float*)d_in[4];
  const float* b_in  = (const float*)d_in[5];
  const float* w_z   = (const float*)d_in[6];
  const float* b_z   = (const float*)d_in[7];
  const float* w_f0  = (const float*)d_in[8];
  const float* b_f0  = (const float*)d_in[9];
  const float* w_f1  = (const float*)d_in[10];
  const float* b_f1  = (const float*)d_in[11];
  const float* w_out = (const float*)d_in[12];
  const float* b_out = (const float*)d_in[13];
  float* out = (float*)d_out;
  char* ws = (char*)d_ws;

  size_t off = 0;
  u16* wts   = (u16*)(ws + off); off += (size_t)15*262144*2;       // 15x fragment-linear bf16
  u16* wtin  = (u16*)(ws + off); off += (size_t)512*64*2;          // lin_in fragment-linear bf16
  u16* featT = (u16*)(ws + off); off += (size_t)2*128*128*512*2;   // transposed features
  u16* alignedF = (u16*)(ws + off); off += (size_t)P_TOTAL*512*2;  // sampled feats, frag-linear
  u16* encF  = (u16*)(ws + off); off += (size_t)P_TOTAL*64*2;      // pos-enc, frag-linear

  k_wtrans15<<<dim3(16,16,15), 64, 0, stream>>>(w_z, w_f0, w_f1, wts);
  k_wtrans_in<<<dim3(2,16,1), 64, 0, stream>>>(w_in, wtin);
  k_featT<<<dim3(64,128,2), 128, 0, stream>>>(feat, featT);
  k_points<<<dim3(P_TOTAL/16), 1024, 0, stream>>>(world, c2w, kmat, featT, alignedF, encF);
  k_net<<<dim3(P_TOTAL/64), 1024, 0, stream>>>(alignedF, encF, wtin, b_in, wts,
      b_z, b_f0, b_f1, w_out, b_out, out);
}